// Round 1
// baseline (211.773 us; speedup 1.0000x reference)
//
#include <hip/hip_runtime.h>
#include <math.h>

#define D 128
#define K 10
#define NB1 2048
#define TPB 256
#define ROWS_PER_TILE 8   // TPB threads * 4 floats / D

// Sorted ascending top-K insert, fully unrolled (static indices only -> stays in VGPRs).
__device__ __forceinline__ void topk_insert(float (&t)[K], float d) {
    if (d < t[K - 1]) {
        t[K - 1] = d;
#pragma unroll
        for (int j = K - 1; j > 0; --j) {
            float a = t[j - 1], b = t[j];
            t[j - 1] = fminf(a, b);
            t[j]     = fmaxf(a, b);
        }
    }
}

__global__ __launch_bounds__(TPB) void knn_stage1(
    const float* __restrict__ x,
    const float* __restrict__ data,
    int nrows,
    float* __restrict__ ws) {
    const int t   = threadIdx.x;
    const int grp = t >> 5;           // 0..7: which row of the 8-row tile
    const int col = (t & 31) * 4;     // fixed column slice for this thread
    const float4 xv = *reinterpret_cast<const float4*>(x + col);

    float best[K];
#pragma unroll
    for (int i = 0; i < K; ++i) best[i] = INFINITY;

    const int ntiles = (nrows + ROWS_PER_TILE - 1) / ROWS_PER_TILE;
    for (int tile = blockIdx.x; tile < ntiles; tile += gridDim.x) {
        const int row = tile * ROWS_PER_TILE + grp;
        if (row < nrows) {  // uniform within each 32-lane group
            const float4 v = *reinterpret_cast<const float4*>(
                data + (size_t)row * D + col);
            float dx = v.x - xv.x, dy = v.y - xv.y;
            float dz = v.z - xv.z, dw = v.w - xv.w;
            float d = dx * dx + dy * dy + dz * dz + dw * dw;
#pragma unroll
            for (int m = 1; m < 32; m <<= 1) d += __shfl_xor(d, m);
            if ((t & 31) == 0) topk_insert(best, d);
        }
    }

    // merge the 8 per-group lists inside the block
    __shared__ float lmerge[(TPB / 32) * K];
    if ((t & 31) == 0) {
#pragma unroll
        for (int i = 0; i < K; ++i) lmerge[grp * K + i] = best[i];
    }
    __syncthreads();
    if (t == 0) {
        float fin[K];
#pragma unroll
        for (int i = 0; i < K; ++i) fin[i] = INFINITY;
        for (int i = 0; i < (TPB / 32) * K; ++i) topk_insert(fin, lmerge[i]);
#pragma unroll
        for (int i = 0; i < K; ++i) ws[(size_t)blockIdx.x * K + i] = fin[i];
    }
}

__global__ __launch_bounds__(TPB) void knn_stage2(
    const float* __restrict__ x,
    const float* __restrict__ y,
    const float* __restrict__ ws,
    int m,
    float* __restrict__ out) {
    const int t    = threadIdx.x;
    const int lane = t & 63;
    const int wid  = t >> 6;

    __shared__ float vals[TPB * K];   // 2560 candidate sq-distances
    __shared__ float red[TPB];
    __shared__ float rmin[TPB / 64];
    __shared__ int   rmini[TPB / 64];

    // per-thread top-K over the candidate pool (coalesced strided scan)
    float best[K];
#pragma unroll
    for (int i = 0; i < K; ++i) best[i] = INFINITY;
    for (int i = t; i < m; i += TPB) topk_insert(best, ws[i]);
#pragma unroll
    for (int i = 0; i < K; ++i) vals[t * K + i] = best[i];

    // ||x - y||^2 reduce
    float dxy = 0.f;
    if (t < D) { float d = x[t] - y[t]; dxy = d * d; }
    red[t] = dxy;
    __syncthreads();
    for (int s = TPB / 2; s > 0; s >>= 1) {
        if (t < s) red[t] += red[t + s];
        __syncthreads();
    }
    float norm_xy = sqrtf(red[0]);  // valid everywhere; only thread 0 uses it

    // 10 rounds of parallel argmin-extract over vals[]
    float sum10 = 0.f;
#pragma unroll 1
    for (int it = 0; it < K; ++it) {
        __syncthreads();
        float mn = INFINITY;
        int   mi = -1;
#pragma unroll
        for (int j = 0; j < K; ++j) {
            float v = vals[t * K + j];
            if (v < mn) { mn = v; mi = t * K + j; }
        }
#pragma unroll
        for (int msk = 1; msk < 64; msk <<= 1) {
            float om = __shfl_xor(mn, msk);
            int   oi = __shfl_xor(mi, msk);
            if (om < mn) { mn = om; mi = oi; }
        }
        if (lane == 0) { rmin[wid] = mn; rmini[wid] = mi; }
        __syncthreads();
        if (t == 0) {
            float gmn = rmin[0];
            int   gmi = rmini[0];
#pragma unroll
            for (int w = 1; w < TPB / 64; ++w) {
                if (rmin[w] < gmn) { gmn = rmin[w]; gmi = rmini[w]; }
            }
            sum10 += sqrtf(gmn);
            vals[gmi] = INFINITY;   // remove this instance; next round finds next-min
        }
    }
    if (t == 0) out[0] = norm_xy * 0.5f + sum10 / (float)K;
}

// Safety fallback: everything in one block (used only if ws is too small).
__global__ __launch_bounds__(TPB) void knn_all(
    const float* __restrict__ x,
    const float* __restrict__ y,
    const float* __restrict__ data,
    int nrows,
    float* __restrict__ out) {
    const int t   = threadIdx.x;
    const int grp = t >> 5;
    const int col = (t & 31) * 4;
    const float4 xv = *reinterpret_cast<const float4*>(x + col);

    float best[K];
#pragma unroll
    for (int i = 0; i < K; ++i) best[i] = INFINITY;

    const int ntiles = (nrows + ROWS_PER_TILE - 1) / ROWS_PER_TILE;
    for (int tile = 0; tile < ntiles; ++tile) {
        const int row = tile * ROWS_PER_TILE + grp;
        if (row < nrows) {
            const float4 v = *reinterpret_cast<const float4*>(
                data + (size_t)row * D + col);
            float dx = v.x - xv.x, dy = v.y - xv.y;
            float dz = v.z - xv.z, dw = v.w - xv.w;
            float d = dx * dx + dy * dy + dz * dz + dw * dw;
#pragma unroll
            for (int m = 1; m < 32; m <<= 1) d += __shfl_xor(d, m);
            if ((t & 31) == 0) topk_insert(best, d);
        }
    }

    __shared__ float lmerge[(TPB / 32) * K];
    __shared__ float red[TPB];
    if ((t & 31) == 0) {
#pragma unroll
        for (int i = 0; i < K; ++i) lmerge[grp * K + i] = best[i];
    }
    float dxy = 0.f;
    if (t < D) { float d = x[t] - y[t]; dxy = d * d; }
    red[t] = dxy;
    __syncthreads();
    for (int s = TPB / 2; s > 0; s >>= 1) {
        if (t < s) red[t] += red[t + s];
        __syncthreads();
    }
    if (t == 0) {
        float fin[K];
#pragma unroll
        for (int i = 0; i < K; ++i) fin[i] = INFINITY;
        for (int i = 0; i < (TPB / 32) * K; ++i) topk_insert(fin, lmerge[i]);
        float sum10 = 0.f;
#pragma unroll
        for (int i = 0; i < K; ++i) sum10 += sqrtf(fin[i]);
        out[0] = sqrtf(red[0]) * 0.5f + sum10 / (float)K;
    }
}

extern "C" void kernel_launch(void* const* d_in, const int* in_sizes, int n_in,
                              void* d_out, int out_size, void* d_ws, size_t ws_size,
                              hipStream_t stream) {
    const float* x    = (const float*)d_in[0];
    const float* y    = (const float*)d_in[1];
    const float* data = (const float*)d_in[2];
    float* out        = (float*)d_out;
    const int nrows   = in_sizes[2] / D;

    const size_t per_block = (size_t)K * sizeof(float);
    if (ws_size >= per_block * 64) {
        int nblocks = (int)((ws_size / per_block < (size_t)NB1)
                                ? (ws_size / per_block)
                                : (size_t)NB1);
        float* ws = (float*)d_ws;
        knn_stage1<<<dim3(nblocks), dim3(TPB), 0, stream>>>(x, data, nrows, ws);
        knn_stage2<<<dim3(1), dim3(TPB), 0, stream>>>(x, y, ws, nblocks * K, out);
    } else {
        knn_all<<<dim3(1), dim3(TPB), 0, stream>>>(x, y, data, nrows, out);
    }
}

// Round 2
// 209.046 us; speedup vs baseline: 1.0130x; 1.0130x over previous
//
#include <hip/hip_runtime.h>
#include <math.h>

#define D 128
#define K 10
#define NB1 2048
#define TPB 256
#define LPR 16                      // lanes per row
#define ROWS_PER_TILE (TPB / LPR)   // 16 rows per block-iteration

typedef float f4 __attribute__((ext_vector_type(4)));

__device__ __forceinline__ f4 ldnt(const float* p) {
    return __builtin_nontemporal_load((const f4*)p);
}

// Sorted ascending top-K insert, fully unrolled (static indices only -> stays in VGPRs).
__device__ __forceinline__ void topk_insert(float (&t)[K], float d) {
    if (d < t[K - 1]) {
        t[K - 1] = d;
#pragma unroll
        for (int j = K - 1; j > 0; --j) {
            float a = t[j - 1], b = t[j];
            t[j - 1] = fminf(a, b);
            t[j]     = fmaxf(a, b);
        }
    }
}

__device__ __forceinline__ float rowdist(f4 a0, f4 a1, f4 xa, f4 xb) {
    f4 d0 = a0 - xa;
    f4 d1 = a1 - xb;
    float d = d0.x * d0.x + d0.y * d0.y + d0.z * d0.z + d0.w * d0.w;
    d += d1.x * d1.x + d1.y * d1.y + d1.z * d1.z + d1.w * d1.w;
#pragma unroll
    for (int m = 1; m < LPR; m <<= 1) d += __shfl_xor(d, m);
    return d;
}

__global__ __launch_bounds__(TPB) void knn_stage1(
    const float* __restrict__ x,
    const float* __restrict__ data,
    int nrows,
    float* __restrict__ ws) {
    const int t   = threadIdx.x;
    const int grp = t / LPR;          // 0..15: row within tile
    const int ln  = t % LPR;          // 0..15
    const int c0  = ln * 4;           // this lane's column slice
    const f4 xa = *(const f4*)(x + c0);
    const f4 xb = *(const f4*)(x + c0 + 64);

    float best[K];
#pragma unroll
    for (int i = 0; i < K; ++i) best[i] = INFINITY;

    const int G          = gridDim.x;
    const int full_tiles = nrows / ROWS_PER_TILE;

    int tile = blockIdx.x;
    if (tile < full_tiles) {
        const float* p = data + (size_t)(tile * ROWS_PER_TILE + grp) * D + c0;
        f4 a0 = ldnt(p);
        f4 a1 = ldnt(p + 64);
        int next = tile + G;
        const size_t step = (size_t)G * ROWS_PER_TILE * D;
        while (next < full_tiles) {
            p += step;
            f4 b0 = ldnt(p);        // prefetch next tile before consuming current
            f4 b1 = ldnt(p + 64);
            float d = rowdist(a0, a1, xa, xb);
            if (ln == 0) topk_insert(best, d);
            a0 = b0; a1 = b1;
            next += G;
        }
        float d = rowdist(a0, a1, xa, xb);
        if (ln == 0) topk_insert(best, d);
    }

    // tail rows (nrows not divisible by ROWS_PER_TILE) — block 0 only
    if (blockIdx.x == 0) {
        const int row = full_tiles * ROWS_PER_TILE + grp;
        if (row < nrows) {
            const float* p = data + (size_t)row * D + c0;
            f4 a0 = ldnt(p);
            f4 a1 = ldnt(p + 64);
            float d = rowdist(a0, a1, xa, xb);
            if (ln == 0) topk_insert(best, d);
        }
    }

    // merge the 16 per-group lists inside the block
    __shared__ float lmerge[ROWS_PER_TILE * K];
    if (ln == 0) {
#pragma unroll
        for (int i = 0; i < K; ++i) lmerge[grp * K + i] = best[i];
    }
    __syncthreads();
    if (t == 0) {
        float fin[K];
#pragma unroll
        for (int i = 0; i < K; ++i) fin[i] = INFINITY;
        for (int i = 0; i < ROWS_PER_TILE * K; ++i) topk_insert(fin, lmerge[i]);
#pragma unroll
        for (int i = 0; i < K; ++i) ws[(size_t)blockIdx.x * K + i] = fin[i];
    }
}

__global__ __launch_bounds__(TPB) void knn_stage2(
    const float* __restrict__ x,
    const float* __restrict__ y,
    const float* __restrict__ ws,
    int m,
    float* __restrict__ out) {
    const int t    = threadIdx.x;
    const int lane = t & 63;
    const int wid  = t >> 6;

    __shared__ float vals[TPB * K];   // candidate sq-distances
    __shared__ float red[TPB];
    __shared__ float rmin[TPB / 64];
    __shared__ int   rmini[TPB / 64];

    float best[K];
#pragma unroll
    for (int i = 0; i < K; ++i) best[i] = INFINITY;
    for (int i = t; i < m; i += TPB) topk_insert(best, ws[i]);
#pragma unroll
    for (int i = 0; i < K; ++i) vals[t * K + i] = best[i];

    // ||x - y||^2 reduce
    float dxy = 0.f;
    if (t < D) { float d = x[t] - y[t]; dxy = d * d; }
    red[t] = dxy;
    __syncthreads();
    for (int s = TPB / 2; s > 0; s >>= 1) {
        if (t < s) red[t] += red[t + s];
        __syncthreads();
    }
    float norm_xy = sqrtf(red[0]);

    // 10 rounds of parallel argmin-extract over vals[]
    float sum10 = 0.f;
#pragma unroll 1
    for (int it = 0; it < K; ++it) {
        __syncthreads();
        float mn = INFINITY;
        int   mi = -1;
#pragma unroll
        for (int j = 0; j < K; ++j) {
            float v = vals[t * K + j];
            if (v < mn) { mn = v; mi = t * K + j; }
        }
#pragma unroll
        for (int msk = 1; msk < 64; msk <<= 1) {
            float om = __shfl_xor(mn, msk);
            int   oi = __shfl_xor(mi, msk);
            if (om < mn) { mn = om; mi = oi; }
        }
        if (lane == 0) { rmin[wid] = mn; rmini[wid] = mi; }
        __syncthreads();
        if (t == 0) {
            float gmn = rmin[0];
            int   gmi = rmini[0];
#pragma unroll
            for (int w = 1; w < TPB / 64; ++w) {
                if (rmin[w] < gmn) { gmn = rmin[w]; gmi = rmini[w]; }
            }
            sum10 += sqrtf(gmn);
            vals[gmi] = INFINITY;
        }
    }
    if (t == 0) out[0] = norm_xy * 0.5f + sum10 / (float)K;
}

// Safety fallback: everything in one block (used only if ws is too small).
__global__ __launch_bounds__(TPB) void knn_all(
    const float* __restrict__ x,
    const float* __restrict__ y,
    const float* __restrict__ data,
    int nrows,
    float* __restrict__ out) {
    const int t   = threadIdx.x;
    const int grp = t / LPR;
    const int ln  = t % LPR;
    const int c0  = ln * 4;
    const f4 xa = *(const f4*)(x + c0);
    const f4 xb = *(const f4*)(x + c0 + 64);

    float best[K];
#pragma unroll
    for (int i = 0; i < K; ++i) best[i] = INFINITY;

    const int ntiles = (nrows + ROWS_PER_TILE - 1) / ROWS_PER_TILE;
    for (int tile = 0; tile < ntiles; ++tile) {
        const int row = tile * ROWS_PER_TILE + grp;
        if (row < nrows) {
            const float* p = data + (size_t)row * D + c0;
            f4 a0 = ldnt(p);
            f4 a1 = ldnt(p + 64);
            float d = rowdist(a0, a1, xa, xb);
            if (ln == 0) topk_insert(best, d);
        }
    }

    __shared__ float lmerge[ROWS_PER_TILE * K];
    __shared__ float red[TPB];
    if (ln == 0) {
#pragma unroll
        for (int i = 0; i < K; ++i) lmerge[grp * K + i] = best[i];
    }
    float dxy = 0.f;
    if (t < D) { float d = x[t] - y[t]; dxy = d * d; }
    red[t] = dxy;
    __syncthreads();
    for (int s = TPB / 2; s > 0; s >>= 1) {
        if (t < s) red[t] += red[t + s];
        __syncthreads();
    }
    if (t == 0) {
        float fin[K];
#pragma unroll
        for (int i = 0; i < K; ++i) fin[i] = INFINITY;
        for (int i = 0; i < ROWS_PER_TILE * K; ++i) topk_insert(fin, lmerge[i]);
        float sum10 = 0.f;
#pragma unroll
        for (int i = 0; i < K; ++i) sum10 += sqrtf(fin[i]);
        out[0] = sqrtf(red[0]) * 0.5f + sum10 / (float)K;
    }
}

extern "C" void kernel_launch(void* const* d_in, const int* in_sizes, int n_in,
                              void* d_out, int out_size, void* d_ws, size_t ws_size,
                              hipStream_t stream) {
    const float* x    = (const float*)d_in[0];
    const float* y    = (const float*)d_in[1];
    const float* data = (const float*)d_in[2];
    float* out        = (float*)d_out;
    const int nrows   = in_sizes[2] / D;

    const size_t per_block = (size_t)K * sizeof(float);
    if (ws_size >= per_block * 64) {
        int nblocks = (int)((ws_size / per_block < (size_t)NB1)
                                ? (ws_size / per_block)
                                : (size_t)NB1);
        float* ws = (float*)d_ws;
        knn_stage1<<<dim3(nblocks), dim3(TPB), 0, stream>>>(x, data, nrows, ws);
        knn_stage2<<<dim3(1), dim3(TPB), 0, stream>>>(x, y, ws, nblocks * K, out);
    } else {
        knn_all<<<dim3(1), dim3(TPB), 0, stream>>>(x, y, data, nrows, out);
    }
}